// Round 1
// baseline (39.677 us; speedup 1.0000x reference)
//
#include <hip/hip_runtime.h>

#define AR 8
#define SEQ 4096
#define BATCH 8192
#define OUTW (AR + SEQ)   // 4104 floats per output row

// ---------------- Phase 1: coefficient matrix via log-doubling ----------------
// C[t][j], t in [0,4096): pred_t = sum_j C[t][j] * y[j]
// Recurrence (right-multiply by companion A):  (R*A)_j = R_{j-1} + R_7 * w_j  (R_{-1}=0)
__global__ __launch_bounds__(512) void coeff_kernel(const float* __restrict__ W,
                                                    float* __restrict__ C) {
    __shared__ float w[AR];
    __shared__ float M[AR][AR];
    __shared__ float Mn[AR][AR];
    const int tid = threadIdx.x;

    if (tid < AR) w[tid] = W[tid];
    __syncthreads();

    // Seed C[0..7] sequentially on thread 0 (trivial work).
    if (tid == 0) {
        float c[AR];
        #pragma unroll
        for (int j = 0; j < AR; ++j) c[j] = w[j];
        for (int t = 0; t < AR; ++t) {
            #pragma unroll
            for (int j = 0; j < AR; ++j) C[t * AR + j] = c[j];
            float c7 = c[AR - 1];
            float nc[AR];
            #pragma unroll
            for (int j = AR - 1; j >= 1; --j) nc[j] = c[j - 1] + c7 * w[j];
            nc[0] = c7 * w[0];
            #pragma unroll
            for (int j = 0; j < AR; ++j) c[j] = nc[j];
        }
    }
    // M = A^8 : thread k (<8) tracks row k = e_k^T A^8.
    if (tid < AR) {
        float r[AR];
        #pragma unroll
        for (int j = 0; j < AR; ++j) r[j] = (j == tid) ? 1.f : 0.f;
        for (int s = 0; s < AR; ++s) {
            float r7 = r[AR - 1];
            float nr[AR];
            #pragma unroll
            for (int j = AR - 1; j >= 1; --j) nr[j] = r[j - 1] + r7 * w[j];
            nr[0] = r7 * w[0];
            #pragma unroll
            for (int j = 0; j < AR; ++j) r[j] = nr[j];
        }
        #pragma unroll
        for (int j = 0; j < AR; ++j) M[tid][j] = r[j];
    }
    __syncthreads();

    // Doubling: rows [m, 2m) = rows [0, m) @ M;  M <- M*M
    for (int m = AR; m < SEQ; m <<= 1) {
        for (int i = tid; i < m; i += blockDim.x) {
            float ci[AR];
            #pragma unroll
            for (int k = 0; k < AR; ++k) ci[k] = C[i * AR + k];
            float r[AR];
            #pragma unroll
            for (int j = 0; j < AR; ++j) {
                float s = 0.f;
                #pragma unroll
                for (int k = 0; k < AR; ++k) s += ci[k] * M[k][j];
                r[j] = s;
            }
            #pragma unroll
            for (int j = 0; j < AR; ++j) C[(m + i) * AR + j] = r[j];
        }
        if (m < SEQ / 2) {           // need M for the next round
            if (tid < 64) {
                int k = tid >> 3, j = tid & 7;
                float s = 0.f;
                #pragma unroll
                for (int q = 0; q < AR; ++q) s += M[k][q] * M[q][j];
                Mn[k][j] = s;
            }
        }
        __syncthreads();             // all reads of M + C writes complete
        if (m < SEQ / 2 && tid < 64) M[tid >> 3][tid & 7] = Mn[tid >> 3][tid & 7];
        __syncthreads();             // M updated before next round
    }
}

// ---------------- Phase 2: out = [y | y @ C^T], coalesced float4 stores ----------------
// Thread: 4 consecutive t (one float4) x 8 batch rows. Block 256 threads covers 1024 t.
__global__ __launch_bounds__(256) void pred_kernel(const float* __restrict__ y,
                                                   const float* __restrict__ C,
                                                   float* __restrict__ out) {
    const int tt = blockIdx.x * 256 + threadIdx.x;   // float4 index along t: 0..1023
    const int t0 = tt * 4;
    const int row0 = blockIdx.y * 8;

    // Load 4 C-rows (32 contiguous floats) into registers.
    float c[4][AR];
    const float4* Cv = reinterpret_cast<const float4*>(C + (size_t)t0 * AR);
    #pragma unroll
    for (int k = 0; k < 4; ++k) {
        float4 a = Cv[k * 2 + 0];
        float4 b = Cv[k * 2 + 1];
        c[k][0] = a.x; c[k][1] = a.y; c[k][2] = a.z; c[k][3] = a.w;
        c[k][4] = b.x; c[k][5] = b.y; c[k][6] = b.z; c[k][7] = b.w;
    }

    #pragma unroll
    for (int r = 0; r < 8; ++r) {
        const int row = row0 + r;
        const float4* yv = reinterpret_cast<const float4*>(y + (size_t)row * AR);
        float4 ya = yv[0], yb = yv[1];
        float yy[AR] = {ya.x, ya.y, ya.z, ya.w, yb.x, yb.y, yb.z, yb.w};
        float pk[4];
        #pragma unroll
        for (int k = 0; k < 4; ++k) {
            float s = 0.f;
            #pragma unroll
            for (int j = 0; j < AR; ++j) s += c[k][j] * yy[j];
            pk[k] = s;
        }
        float4 p = make_float4(pk[0], pk[1], pk[2], pk[3]);
        *reinterpret_cast<float4*>(out + (size_t)row * OUTW + AR + t0) = p;
    }

    // Copy the y-head (first 8 columns) once per row, by blocks in the first t-tile.
    if (blockIdx.x == 0 && threadIdx.x < 16) {
        int r = threadIdx.x >> 1, part = threadIdx.x & 1;
        const int row = row0 + r;
        reinterpret_cast<float4*>(out + (size_t)row * OUTW)[part] =
            reinterpret_cast<const float4*>(y + (size_t)row * AR)[part];
    }
}

extern "C" void kernel_launch(void* const* d_in, const int* in_sizes, int n_in,
                              void* d_out, int out_size, void* d_ws, size_t ws_size,
                              hipStream_t stream) {
    const float* y = (const float*)d_in[0];
    // d_in[1] = u  -- unused by the reference computation
    const float* W = (const float*)d_in[2];
    float* out = (float*)d_out;
    float* C = (float*)d_ws;                      // 4096*8 floats = 128 KB scratch

    coeff_kernel<<<1, 512, 0, stream>>>(W, C);
    pred_kernel<<<dim3(SEQ / 1024, BATCH / 8), 256, 0, stream>>>(y, C, out);
}